// Round 2
// baseline (415.585 us; speedup 1.0000x reference)
//
#include <hip/hip_runtime.h>
#include <stdint.h>

#define K_DIM 4096
#define M_TOK 8192
#define N_OUT 4096

typedef int v4i __attribute__((ext_vector_type(4)));

// ---- workspace layout (bytes) ----
// q   : int8 [8192][4096]   @ 0          (33554432)
// tw  : int8 [4096][4096]   @ 33554432   (16777216)
// rs  : float[8192]         @ 50331648   (32768)
// acc : double              @ 50364416   (8)

#define BAR()                                     \
    do {                                          \
        asm volatile("" ::: "memory");            \
        __builtin_amdgcn_s_barrier();             \
        asm volatile("" ::: "memory");            \
    } while (0)

__device__ __forceinline__ void gload_lds16(const void* g, void* l) {
    auto gp = reinterpret_cast<const __attribute__((address_space(1))) uint32_t*>(
        reinterpret_cast<uintptr_t>(g));
    auto lp = reinterpret_cast<__attribute__((address_space(3))) uint32_t*>(
        reinterpret_cast<uintptr_t>(l));
    __builtin_amdgcn_global_load_lds(gp, lp, 16, 0, 0);
}

// --- per-token activation quantization: q = clip(round(x*s),-128,127), rs = 1/s ---
// also zero-inits the fp64 |w|-sum accumulator (runs before wabs_sum in stream order)
__global__ __launch_bounds__(256) void quant_act(const float* __restrict__ x,
                                                 int8_t* __restrict__ q,
                                                 float* __restrict__ rs,
                                                 double* __restrict__ acc) {
    const int token = blockIdx.x;
    const int t = threadIdx.x;
    if (token == 0 && t == 0) *acc = 0.0;
    const float4* x4 = (const float4*)(x + (size_t)token * K_DIM);
    float4 v[4];
    float m = 0.0f;
#pragma unroll
    for (int r = 0; r < 4; ++r) {
        v[r] = x4[t + 256 * r];
        m = fmaxf(m, fmaxf(fmaxf(fabsf(v[r].x), fabsf(v[r].y)),
                           fmaxf(fabsf(v[r].z), fabsf(v[r].w))));
    }
#pragma unroll
    for (int off = 32; off; off >>= 1) m = fmaxf(m, __shfl_down(m, off, 64));
    __shared__ float wmax[4];
    __shared__ float smax;
    if ((t & 63) == 0) wmax[t >> 6] = m;
    __syncthreads();
    if (t == 0) smax = fmaxf(fmaxf(wmax[0], wmax[1]), fmaxf(wmax[2], wmax[3]));
    __syncthreads();
    const float s = 127.0f / fmaxf(smax, 1e-5f);
    char4* q4 = (char4*)(q + (size_t)token * K_DIM);
#pragma unroll
    for (int r = 0; r < 4; ++r) {
        float4 f = v[r];
        char4 c;
        c.x = (signed char)fminf(fmaxf(rintf(f.x * s), -128.0f), 127.0f);
        c.y = (signed char)fminf(fmaxf(rintf(f.y * s), -128.0f), 127.0f);
        c.z = (signed char)fminf(fmaxf(rintf(f.z * s), -128.0f), 127.0f);
        c.w = (signed char)fminf(fmaxf(rintf(f.w * s), -128.0f), 127.0f);
        q4[t + 256 * r] = c;
    }
    if (t == 0) rs[token] = 1.0f / s;
}

// --- sum |w| into fp64 accumulator ---
__global__ __launch_bounds__(256) void wabs_sum(const float* __restrict__ w,
                                                double* __restrict__ acc) {
    const size_t n4 = (size_t)N_OUT * K_DIM / 4;
    const size_t stride = (size_t)gridDim.x * 256;
    const float4* w4 = (const float4*)w;
    float sum = 0.0f;
    for (size_t j = (size_t)blockIdx.x * 256 + threadIdx.x; j < n4; j += stride) {
        float4 f = w4[j];
        sum += fabsf(f.x) + fabsf(f.y) + fabsf(f.z) + fabsf(f.w);
    }
    double d = (double)sum;
#pragma unroll
    for (int off = 32; off; off >>= 1) d += __shfl_down(d, off, 64);
    __shared__ double wsum[4];
    const int t = threadIdx.x;
    if ((t & 63) == 0) wsum[t >> 6] = d;
    __syncthreads();
    if (t == 0) atomicAdd(acc, wsum[0] + wsum[1] + wsum[2] + wsum[3]);
}

// --- ternarize: tw = clip(round(w*scale_w),-1,1), scale_w = 1/clip(mean|w|,eps) ---
__global__ __launch_bounds__(256) void ternarize(const float* __restrict__ w,
                                                 int8_t* __restrict__ tw,
                                                 const double* __restrict__ acc) {
    const double mean = *acc * (1.0 / ((double)N_OUT * (double)K_DIM));
    const float sw = 1.0f / fmaxf((float)mean, 1e-5f);
    const size_t i = (size_t)blockIdx.x * 256 + threadIdx.x;
    const float4* w4 = (const float4*)w;
    char4* t4 = (char4*)tw;
    float4 f = w4[i];
    char4 c;
    c.x = (signed char)fminf(fmaxf(rintf(f.x * sw), -1.0f), 1.0f);
    c.y = (signed char)fminf(fmaxf(rintf(f.y * sw), -1.0f), 1.0f);
    c.z = (signed char)fminf(fmaxf(rintf(f.z * sw), -1.0f), 1.0f);
    c.w = (signed char)fminf(fmaxf(rintf(f.w * sw), -1.0f), 1.0f);
    t4[i] = c;
}

// --- i8 GEMM, deep-pipelined (T1+T2+T3+T4+T5) ---
// 256x256 block tile, BK=64 (64-B LDS rows), 512 threads = 8 waves (4M x 2N),
// wave tile 64x128, 16x16x64 i8 MFMA.
// LDS: 4-slot ring, each slot = A[256][64] + B[256][64] = 32 KB -> 128 KB total.
// Prefetch depth 3 K-tiles; staging for tile t+3 targets slot (t+3)&3 == (t-1)&3,
// whose reads finished before tile t began (barrier) -> race-free by construction.
// Counted vmcnt: vmcnt(8) once per tile (4 loads/thread/tile, <=12 in flight).
// Swizzle: 16-B chunk c of row r lives at slot c ^ (r&3) ^ ((r>>2)&3); source
// column pre-swizzled (global_load_lds dest must stay lane-linear). Fragment
// ds_read_b128: 16-lane groups hit 8 bank-quads x 2 = 2-way = free.
__global__ __launch_bounds__(512, 2) void gemm_i8(const int8_t* __restrict__ A,
                                                  const int8_t* __restrict__ B,
                                                  const float* __restrict__ rs,
                                                  const double* __restrict__ acc,
                                                  float* __restrict__ out) {
    // T1: bijective XCD swizzle (512 wgs, 8 XCDs, 64 contiguous wgs per XCD)
    const int nwgx = N_OUT / 256;  // 16
    const int orig = blockIdx.y * nwgx + blockIdx.x;
    const int wg = (orig & 7) * 64 + (orig >> 3);
    const int bm = (wg / nwgx) * 256;
    const int bn = (wg % nwgx) * 256;

    __shared__ int8_t smem[4][2][16384];  // [slot][A,B][256 rows x 64 B]

    const int t0 = threadIdx.x;
    const int lane = t0 & 63;
    const int wave = t0 >> 6;
    const int wm = (wave >> 1) * 64;    // 0,64,128,192
    const int wn = (wave & 1) * 128;    // 0,128

    v4i accv[4][8] = {};

    // staging constants: thread t0 -> row R0 = t0>>2 (+128 for round 1),
    // slot-chunk t0&3 holds source chunk (t0&3)^(R&3)^((R>>2)&3); same for r=0,1
    // (row+128 leaves both XOR terms unchanged: 128 == 0 mod 16).
    const int R0 = t0 >> 2;
    const int scol = (((t0 & 3) ^ (R0 & 3) ^ ((R0 >> 2) & 3)) << 4);
    const int8_t* Ag = A + (size_t)(bm + R0) * K_DIM + scol;
    const int8_t* Bg = B + (size_t)(bn + R0) * K_DIM + scol;
    int8_t* ldst = &smem[0][0][0] + (size_t)t0 * 16;  // + slot*32768 (+16384 for B, +8192 for r=1)

    // fragment read constants
    const int fr = lane & 15;
    const int co = (((lane >> 4) ^ (fr & 3) ^ (fr >> 2)) << 4);

    // prologue: stage tiles 0..2 into slots 0..2 (12 loads/thread)
#pragma unroll
    for (int pt = 0; pt < 3; ++pt) {
        const int k0 = pt * 64;
        int8_t* sb = ldst + pt * 32768;
        gload_lds16(Ag + k0, sb);
        gload_lds16(Ag + k0 + (size_t)128 * K_DIM, sb + 8192);
        gload_lds16(Bg + k0, sb + 16384);
        gload_lds16(Bg + k0 + (size_t)128 * K_DIM, sb + 24576);
    }
    asm volatile("s_waitcnt vmcnt(8)" ::: "memory");  // tile 0 resident
    BAR();

#pragma unroll 1
    for (int t = 0; t < 64; ++t) {
        const int slot = t & 3;
        const int8_t* aB = &smem[slot][0][0];
        const int8_t* bB = &smem[slot][1][0];
        const bool st = (t < 61);
        const int ks = (t + 3) * 64;
        int8_t* sb = ldst + ((t + 3) & 3) * 32768;

        v4i af[4];
#pragma unroll
        for (int p = 0; p < 4; ++p) {
            if (p == 0) {
#pragma unroll
                for (int i = 0; i < 4; ++i)
                    af[i] = *(const v4i*)(aB + (wm + i * 16 + fr) * 64 + co);
            }
            v4i b0 = *(const v4i*)(bB + (wn + (2 * p) * 16 + fr) * 64 + co);
            v4i b1 = *(const v4i*)(bB + (wn + (2 * p + 1) * 16 + fr) * 64 + co);
            if (st) {  // one staging round per phase: A r0, A r1, B r0, B r1
                if (p == 0) gload_lds16(Ag + ks, sb);
                else if (p == 1) gload_lds16(Ag + ks + (size_t)128 * K_DIM, sb + 8192);
                else if (p == 2) gload_lds16(Bg + ks, sb + 16384);
                else gload_lds16(Bg + ks + (size_t)128 * K_DIM, sb + 24576);
            }
            BAR();
            __builtin_amdgcn_s_setprio(1);
#pragma unroll
            for (int i = 0; i < 4; ++i) {
                accv[i][2 * p] = __builtin_amdgcn_mfma_i32_16x16x64_i8(af[i], b0, accv[i][2 * p], 0, 0, 0);
                accv[i][2 * p + 1] = __builtin_amdgcn_mfma_i32_16x16x64_i8(af[i], b1, accv[i][2 * p + 1], 0, 0, 0);
            }
            __builtin_amdgcn_s_setprio(0);
            if (p < 3) BAR();
        }
        // tile-end: ensure next tile resident; never vmcnt(0) in steady state
        if (t < 61) asm volatile("s_waitcnt vmcnt(8)" ::: "memory");
        else if (t == 61) asm volatile("s_waitcnt vmcnt(4)" ::: "memory");
        else if (t == 62) asm volatile("s_waitcnt vmcnt(0)" ::: "memory");
        if (t < 63) BAR();
    }

    // epilogue: C/D layout col=lane&15, row=(lane>>4)*4+reg
    const double mean = *acc * (1.0 / ((double)N_OUT * (double)K_DIM));
    const float wmean = fmaxf((float)mean, 1e-5f);  // == 1/scale_w
    const int crow0 = (lane >> 4) * 4;
    const int ccol = lane & 15;
#pragma unroll
    for (int i = 0; i < 4; ++i) {
        const int rbase = bm + wm + i * 16 + crow0;
#pragma unroll
        for (int reg = 0; reg < 4; ++reg) {
            const int r = rbase + reg;
            const float scale = rs[r] * wmean;
            float* orow = out + (size_t)r * N_OUT + bn + wn + ccol;
#pragma unroll
            for (int j = 0; j < 8; ++j)
                orow[j * 16] = (float)accv[i][j][reg] * scale;
        }
    }
}

extern "C" void kernel_launch(void* const* d_in, const int* in_sizes, int n_in,
                              void* d_out, int out_size, void* d_ws, size_t ws_size,
                              hipStream_t stream) {
    const float* x = (const float*)d_in[0];
    const float* w = (const float*)d_in[1];
    float* out = (float*)d_out;
    char* ws = (char*)d_ws;
    int8_t* q = (int8_t*)ws;
    int8_t* tw = (int8_t*)(ws + 33554432);
    float* rs = (float*)(ws + 50331648);
    double* acc = (double*)(ws + 50364416);

    hipLaunchKernelGGL(quant_act, dim3(M_TOK), dim3(256), 0, stream, x, q, rs, acc);
    hipLaunchKernelGGL(wabs_sum, dim3(1024), dim3(256), 0, stream, w, acc);
    hipLaunchKernelGGL(ternarize, dim3((N_OUT * (size_t)K_DIM / 4) / 256), dim3(256), 0, stream, w, tw, acc);
    hipLaunchKernelGGL(gemm_i8, dim3(N_OUT / 256, M_TOK / 256), dim3(512), 0, stream, q, tw, rs, acc, out);
}

// Round 3
// 410.616 us; speedup vs baseline: 1.0121x; 1.0121x over previous
//
#include <hip/hip_runtime.h>
#include <stdint.h>

#define K_DIM 4096
#define M_TOK 8192
#define N_OUT 4096

typedef int v4i __attribute__((ext_vector_type(4)));
typedef int v16i __attribute__((ext_vector_type(16)));

// ---- workspace layout (bytes) ----
// q   : int8 [8192][4096]   @ 0          (33554432)
// tw  : int8 [4096][4096]   @ 33554432   (16777216)
// rs  : float[8192]         @ 50331648   (32768)
// acc : double              @ 50364416   (8)

#define BAR()                                     \
    do {                                          \
        asm volatile("" ::: "memory");            \
        __builtin_amdgcn_s_barrier();             \
        asm volatile("" ::: "memory");            \
    } while (0)

__device__ __forceinline__ void gload_lds16(const void* g, void* l) {
    auto gp = reinterpret_cast<const __attribute__((address_space(1))) uint32_t*>(
        reinterpret_cast<uintptr_t>(g));
    auto lp = reinterpret_cast<__attribute__((address_space(3))) uint32_t*>(
        reinterpret_cast<uintptr_t>(l));
    __builtin_amdgcn_global_load_lds(gp, lp, 16, 0, 0);
}

// --- per-token activation quantization: q = clip(round(x*s),-128,127), rs = 1/s ---
// also zero-inits the fp64 |w|-sum accumulator (runs before wabs_sum in stream order)
__global__ __launch_bounds__(256) void quant_act(const float* __restrict__ x,
                                                 int8_t* __restrict__ q,
                                                 float* __restrict__ rs,
                                                 double* __restrict__ acc) {
    const int token = blockIdx.x;
    const int t = threadIdx.x;
    if (token == 0 && t == 0) *acc = 0.0;
    const float4* x4 = (const float4*)(x + (size_t)token * K_DIM);
    float4 v[4];
    float m = 0.0f;
#pragma unroll
    for (int r = 0; r < 4; ++r) {
        v[r] = x4[t + 256 * r];
        m = fmaxf(m, fmaxf(fmaxf(fabsf(v[r].x), fabsf(v[r].y)),
                           fmaxf(fabsf(v[r].z), fabsf(v[r].w))));
    }
#pragma unroll
    for (int off = 32; off; off >>= 1) m = fmaxf(m, __shfl_down(m, off, 64));
    __shared__ float wmax[4];
    __shared__ float smax;
    if ((t & 63) == 0) wmax[t >> 6] = m;
    __syncthreads();
    if (t == 0) smax = fmaxf(fmaxf(wmax[0], wmax[1]), fmaxf(wmax[2], wmax[3]));
    __syncthreads();
    const float s = 127.0f / fmaxf(smax, 1e-5f);
    char4* q4 = (char4*)(q + (size_t)token * K_DIM);
#pragma unroll
    for (int r = 0; r < 4; ++r) {
        float4 f = v[r];
        char4 c;
        c.x = (signed char)fminf(fmaxf(rintf(f.x * s), -128.0f), 127.0f);
        c.y = (signed char)fminf(fmaxf(rintf(f.y * s), -128.0f), 127.0f);
        c.z = (signed char)fminf(fmaxf(rintf(f.z * s), -128.0f), 127.0f);
        c.w = (signed char)fminf(fmaxf(rintf(f.w * s), -128.0f), 127.0f);
        q4[t + 256 * r] = c;
    }
    if (t == 0) rs[token] = 1.0f / s;
}

// --- sum |w| into fp64 accumulator ---
__global__ __launch_bounds__(256) void wabs_sum(const float* __restrict__ w,
                                                double* __restrict__ acc) {
    const size_t n4 = (size_t)N_OUT * K_DIM / 4;
    const size_t stride = (size_t)gridDim.x * 256;
    const float4* w4 = (const float4*)w;
    float sum = 0.0f;
    for (size_t j = (size_t)blockIdx.x * 256 + threadIdx.x; j < n4; j += stride) {
        float4 f = w4[j];
        sum += fabsf(f.x) + fabsf(f.y) + fabsf(f.z) + fabsf(f.w);
    }
    double d = (double)sum;
#pragma unroll
    for (int off = 32; off; off >>= 1) d += __shfl_down(d, off, 64);
    __shared__ double wsum[4];
    const int t = threadIdx.x;
    if ((t & 63) == 0) wsum[t >> 6] = d;
    __syncthreads();
    if (t == 0) atomicAdd(acc, wsum[0] + wsum[1] + wsum[2] + wsum[3]);
}

// --- ternarize: tw = clip(round(w*scale_w),-1,1), scale_w = 1/clip(mean|w|,eps) ---
__global__ __launch_bounds__(256) void ternarize(const float* __restrict__ w,
                                                 int8_t* __restrict__ tw,
                                                 const double* __restrict__ acc) {
    const double mean = *acc * (1.0 / ((double)N_OUT * (double)K_DIM));
    const float sw = 1.0f / fmaxf((float)mean, 1e-5f);
    const size_t i = (size_t)blockIdx.x * 256 + threadIdx.x;
    const float4* w4 = (const float4*)w;
    char4* t4 = (char4*)tw;
    float4 f = w4[i];
    char4 c;
    c.x = (signed char)fminf(fmaxf(rintf(f.x * sw), -1.0f), 1.0f);
    c.y = (signed char)fminf(fmaxf(rintf(f.y * sw), -1.0f), 1.0f);
    c.z = (signed char)fminf(fmaxf(rintf(f.z * sw), -1.0f), 1.0f);
    c.w = (signed char)fminf(fmaxf(rintf(f.w * sw), -1.0f), 1.0f);
    t4[i] = c;
}

// --- i8 GEMM, deep-pipelined, 32x32x32 MFMA ---
// 256x256 block tile, BK=64 (64-B LDS rows), 512 threads = 8 waves (4M x 2N),
// wave tile 64x128 = 2x4 subtiles of 32x32, mfma_i32_32x32x32_i8.
// LDS: 4-slot ring, each slot = A[256][64] + B[256][64] = 32 KB -> 128 KB total.
// Prefetch depth 3; staging for tile t+3 targets slot (t+3)&3 == (t-1)&3, whose
// reads finished before tile t began -> race-free. vmcnt(8) once per tile.
// 2 phases/tile (one per 32-wide k-slice): {6 ds_read_b128; 2 gload_lds; BAR;
// setprio(1); 8 MFMA; setprio(0); BAR}. 4 barriers/tile (vs 8 at 16x16x64),
// MFMA run per phase 432 SIMD-cyc (vs 320) -> better MFMA:overhead ratio,
// and the 32x32 shape's measured ceiling is 4404 vs 3944 TOPS.
// Swizzle: 16-B chunk c of row r stored at slot c ^ (r&3) ^ ((r>>2)&3); source
// column pre-swizzled (global_load_lds dest stays lane-linear). Fragment reads
// (row = l&31, chunk = ks*2 + (l>>5)) hit all 8 bank-quads per 8-lane subgroup.
__global__ __launch_bounds__(512, 2) void gemm_i8(const int8_t* __restrict__ A,
                                                  const int8_t* __restrict__ B,
                                                  const float* __restrict__ rs,
                                                  const double* __restrict__ acc,
                                                  float* __restrict__ out) {
    // T1: bijective XCD swizzle (512 wgs, 8 XCDs, 64 contiguous wgs per XCD)
    const int nwgx = N_OUT / 256;  // 16
    const int orig = blockIdx.y * nwgx + blockIdx.x;
    const int wg = (orig & 7) * 64 + (orig >> 3);
    const int bm = (wg / nwgx) * 256;
    const int bn = (wg % nwgx) * 256;

    __shared__ int8_t smem[4][2][16384];  // [slot][A,B][256 rows x 64 B]

    const int t0 = threadIdx.x;
    const int lane = t0 & 63;
    const int wave = t0 >> 6;
    const int wm = (wave >> 1) * 64;    // 0,64,128,192
    const int wn = (wave & 1) * 128;    // 0,128

    v16i accv[2][4] = {};

    // staging: thread t0 -> row R0 = t0>>2 (+128 for round 1), slot-chunk t0&3
    // holds source chunk (t0&3)^(R&3)^((R>>2)&3); row+128 leaves both terms
    // unchanged (128 == 0 mod 16).
    const int R0 = t0 >> 2;
    const int scol = (((t0 & 3) ^ (R0 & 3) ^ ((R0 >> 2) & 3)) << 4);
    const int8_t* Ag = A + (size_t)(bm + R0) * K_DIM + scol;
    const int8_t* Bg = B + (size_t)(bn + R0) * K_DIM + scol;
    int8_t* ldst = &smem[0][0][0] + (size_t)t0 * 16;  // + slot*32768 (+16384 for B, +8192 for r=1)

    // fragment read constants (32x32x32: A row = lane&31, 16B at k=(lane>>5)*16)
    const int l31 = lane & 31;
    const int lh = lane >> 5;
    const int sx = (l31 & 3) ^ ((l31 >> 2) & 3);  // row-swizzle, lane-only (wm/wn/m*32 == 0 mod 16)

    // prologue: stage tiles 0..2 into slots 0..2 (12 loads/thread)
#pragma unroll
    for (int pt = 0; pt < 3; ++pt) {
        const int k0 = pt * 64;
        int8_t* sb = ldst + pt * 32768;
        gload_lds16(Ag + k0, sb);
        gload_lds16(Ag + k0 + (size_t)128 * K_DIM, sb + 8192);
        gload_lds16(Bg + k0, sb + 16384);
        gload_lds16(Bg + k0 + (size_t)128 * K_DIM, sb + 24576);
    }
    asm volatile("s_waitcnt vmcnt(8)" ::: "memory");  // tile 0 resident
    BAR();

#pragma unroll 1
    for (int t = 0; t < 64; ++t) {
        const int slot = t & 3;
        const int8_t* aB = &smem[slot][0][0];
        const int8_t* bB = &smem[slot][1][0];
        const bool st = (t < 61);
        const int ksg = (t + 3) * 64;
        int8_t* sb = ldst + ((t + 3) & 3) * 32768;

#pragma unroll
        for (int ks = 0; ks < 2; ++ks) {
            const int co = (((ks * 2 + lh) ^ sx) << 4);
            v4i af0 = *(const v4i*)(aB + (wm + l31) * 64 + co);
            v4i af1 = *(const v4i*)(aB + (wm + 32 + l31) * 64 + co);
            v4i bf[4];
#pragma unroll
            for (int n = 0; n < 4; ++n)
                bf[n] = *(const v4i*)(bB + (wn + n * 32 + l31) * 64 + co);
            if (st) {  // 2 staging loads per phase (A in ks0, B in ks1)
                if (ks == 0) {
                    gload_lds16(Ag + ksg, sb);
                    gload_lds16(Ag + ksg + (size_t)128 * K_DIM, sb + 8192);
                } else {
                    gload_lds16(Bg + ksg, sb + 16384);
                    gload_lds16(Bg + ksg + (size_t)128 * K_DIM, sb + 24576);
                }
            }
            BAR();
            __builtin_amdgcn_s_setprio(1);
#pragma unroll
            for (int n = 0; n < 4; ++n) {
                accv[0][n] = __builtin_amdgcn_mfma_i32_32x32x32_i8(af0, bf[n], accv[0][n], 0, 0, 0);
                accv[1][n] = __builtin_amdgcn_mfma_i32_32x32x32_i8(af1, bf[n], accv[1][n], 0, 0, 0);
            }
            __builtin_amdgcn_s_setprio(0);
            if (ks == 0) BAR();
        }
        // tile-end: ensure next tile resident; never vmcnt(0) in steady state
        if (t < 61) asm volatile("s_waitcnt vmcnt(8)" ::: "memory");
        else if (t == 61) asm volatile("s_waitcnt vmcnt(4)" ::: "memory");
        else if (t == 62) asm volatile("s_waitcnt vmcnt(0)" ::: "memory");
        if (t < 63) BAR();
    }

    // epilogue: 32x32 C/D layout col=lane&31, row=(reg&3)+8*(reg>>2)+4*(lane>>5)
    const double mean = *acc * (1.0 / ((double)N_OUT * (double)K_DIM));
    const float wmean = fmaxf((float)mean, 1e-5f);  // == 1/scale_w
#pragma unroll
    for (int m = 0; m < 2; ++m) {
#pragma unroll
        for (int r = 0; r < 16; ++r) {
            const int row = bm + wm + m * 32 + (r & 3) + 8 * (r >> 2) + 4 * lh;
            const float scale = rs[row] * wmean;
            float* orow = out + (size_t)row * N_OUT + bn + wn + l31;
#pragma unroll
            for (int n = 0; n < 4; ++n)
                orow[n * 32] = (float)accv[m][n][r] * scale;
        }
    }
}

extern "C" void kernel_launch(void* const* d_in, const int* in_sizes, int n_in,
                              void* d_out, int out_size, void* d_ws, size_t ws_size,
                              hipStream_t stream) {
    const float* x = (const float*)d_in[0];
    const float* w = (const float*)d_in[1];
    float* out = (float*)d_out;
    char* ws = (char*)d_ws;
    int8_t* q = (int8_t*)ws;
    int8_t* tw = (int8_t*)(ws + 33554432);
    float* rs = (float*)(ws + 50331648);
    double* acc = (double*)(ws + 50364416);

    hipLaunchKernelGGL(quant_act, dim3(M_TOK), dim3(256), 0, stream, x, q, rs, acc);
    hipLaunchKernelGGL(wabs_sum, dim3(1024), dim3(256), 0, stream, w, acc);
    hipLaunchKernelGGL(ternarize, dim3((N_OUT * (size_t)K_DIM / 4) / 256), dim3(256), 0, stream, w, tw, acc);
    hipLaunchKernelGGL(gemm_i8, dim3(N_OUT / 256, M_TOK / 256), dim3(512), 0, stream, q, tw, rs, acc, out);
}

// Round 4
// 405.113 us; speedup vs baseline: 1.0258x; 1.0136x over previous
//
#include <hip/hip_runtime.h>
#include <stdint.h>

#define K_DIM 4096
#define M_TOK 8192
#define N_OUT 4096

typedef int v4i __attribute__((ext_vector_type(4)));
typedef int v16i __attribute__((ext_vector_type(16)));

// ---- workspace layout (bytes) ----
// q       : int8 [8192][4096]   @ 0          (33554432)
// tw      : int8 [4096][4096]   @ 33554432   (16777216)
// rs      : float[8192]         @ 50331648   (32768)
// partial : double[1024]        @ 50364416   (8192)
// meanp   : float               @ 50372608   (4)

#define BAR()                                     \
    do {                                          \
        asm volatile("" ::: "memory");            \
        __builtin_amdgcn_s_barrier();             \
        asm volatile("" ::: "memory");            \
    } while (0)

__device__ __forceinline__ void gload_lds16(const void* g, void* l) {
    auto gp = reinterpret_cast<const __attribute__((address_space(1))) uint32_t*>(
        reinterpret_cast<uintptr_t>(g));
    auto lp = reinterpret_cast<__attribute__((address_space(3))) uint32_t*>(
        reinterpret_cast<uintptr_t>(l));
    __builtin_amdgcn_global_load_lds(gp, lp, 16, 0, 0);
}

// --- per-token activation quantization: q = clip(round(x*s),-128,127), rs = 1/s ---
__global__ __launch_bounds__(256) void quant_act(const float* __restrict__ x,
                                                 int8_t* __restrict__ q,
                                                 float* __restrict__ rs) {
    const int token = blockIdx.x;
    const int t = threadIdx.x;
    const float4* x4 = (const float4*)(x + (size_t)token * K_DIM);
    float4 v[4];
    float m = 0.0f;
#pragma unroll
    for (int r = 0; r < 4; ++r) {
        v[r] = x4[t + 256 * r];
        m = fmaxf(m, fmaxf(fmaxf(fabsf(v[r].x), fabsf(v[r].y)),
                           fmaxf(fabsf(v[r].z), fabsf(v[r].w))));
    }
#pragma unroll
    for (int off = 32; off; off >>= 1) m = fmaxf(m, __shfl_down(m, off, 64));
    __shared__ float wmax[4];
    __shared__ float smax;
    if ((t & 63) == 0) wmax[t >> 6] = m;
    __syncthreads();
    if (t == 0) smax = fmaxf(fmaxf(wmax[0], wmax[1]), fmaxf(wmax[2], wmax[3]));
    __syncthreads();
    const float s = 127.0f / fmaxf(smax, 1e-5f);
    char4* q4 = (char4*)(q + (size_t)token * K_DIM);
#pragma unroll
    for (int r = 0; r < 4; ++r) {
        float4 f = v[r];
        char4 c;
        c.x = (signed char)fminf(fmaxf(rintf(f.x * s), -128.0f), 127.0f);
        c.y = (signed char)fminf(fmaxf(rintf(f.y * s), -128.0f), 127.0f);
        c.z = (signed char)fminf(fmaxf(rintf(f.z * s), -128.0f), 127.0f);
        c.w = (signed char)fminf(fmaxf(rintf(f.w * s), -128.0f), 127.0f);
        q4[t + 256 * r] = c;
    }
    if (t == 0) rs[token] = 1.0f / s;
}

// --- sum |w| partials: 1024 blocks, NO atomics (per-block partial to global) ---
__global__ __launch_bounds__(256) void wabs_sum(const float* __restrict__ w,
                                                double* __restrict__ partial) {
    const size_t n4 = (size_t)N_OUT * K_DIM / 4;
    const size_t stride = (size_t)gridDim.x * 256;
    const float4* w4 = (const float4*)w;
    float sum = 0.0f;
    for (size_t j = (size_t)blockIdx.x * 256 + threadIdx.x; j < n4; j += stride) {
        float4 f = w4[j];
        sum += fabsf(f.x) + fabsf(f.y) + fabsf(f.z) + fabsf(f.w);
    }
    double d = (double)sum;
#pragma unroll
    for (int off = 32; off; off >>= 1) d += __shfl_down(d, off, 64);
    __shared__ double wsum[4];
    const int t = threadIdx.x;
    if ((t & 63) == 0) wsum[t >> 6] = d;
    __syncthreads();
    if (t == 0) partial[blockIdx.x] = wsum[0] + wsum[1] + wsum[2] + wsum[3];
}

// --- ternarize: every block sums the 1024 partials (identical deterministic
// order -> identical mean), then tw = clip(round(w*sw),-1,1). Block 0 also
// publishes clamped mean (float) for the GEMM epilogue. 4 float4/thread. ---
__global__ __launch_bounds__(256) void ternarize(const float* __restrict__ w,
                                                 int8_t* __restrict__ tw,
                                                 const double* __restrict__ partial,
                                                 float* __restrict__ meanp) {
    const int t = threadIdx.x;
    double d = partial[t] + partial[t + 256] + partial[t + 512] + partial[t + 768];
#pragma unroll
    for (int off = 32; off; off >>= 1) d += __shfl_down(d, off, 64);
    __shared__ double pr[4];
    if ((t & 63) == 0) pr[t >> 6] = d;
    __syncthreads();
    const double tot = pr[0] + pr[1] + pr[2] + pr[3];
    const float mean = fmaxf((float)(tot * (1.0 / ((double)N_OUT * (double)K_DIM))), 1e-5f);
    const float sw = 1.0f / mean;
    if (blockIdx.x == 0 && t == 0) *meanp = mean;
    const float4* w4 = (const float4*)w;
    char4* t4 = (char4*)tw;
    const size_t base = (size_t)blockIdx.x * 1024 + t;
#pragma unroll
    for (int r = 0; r < 4; ++r) {
        float4 f = w4[base + r * 256];
        char4 c;
        c.x = (signed char)fminf(fmaxf(rintf(f.x * sw), -1.0f), 1.0f);
        c.y = (signed char)fminf(fmaxf(rintf(f.y * sw), -1.0f), 1.0f);
        c.z = (signed char)fminf(fmaxf(rintf(f.z * sw), -1.0f), 1.0f);
        c.w = (signed char)fminf(fmaxf(rintf(f.w * sw), -1.0f), 1.0f);
        t4[base + r * 256] = c;
    }
}

// --- i8 GEMM, deep-pipelined, 32x32x32 MFMA, de-lockstepped ---
// 256x256 block tile, BK=64, 512 threads = 8 waves (4M x 2N), wave tile 64x128.
// LDS: 4-slot ring (32 KB/slot, 128 KB). Prefetch depth 3; staging at tile t
// targets slot (t+3)&3 == (t-1)&3, whose last LDS read was before tile t-1's
// barrier -> race-free with ONE barrier per tile.
// Per tile: {4 gload_lds; 6 ds_read (ks1 frags); 8 MFMA (ks0, regs loaded last
// tile); vmcnt(8); BAR; 6 ds_read (next tile ks0 frags); 8 MFMA (ks1)}.
// Every MFMA cluster's operands were ds_read a half-tile (~300 cyc) earlier ->
// no exposed LDS latency; 2 waves/SIMD drift anti-phase between barriers.
// Swizzle: 16-B chunk c of row r stored at c ^ (r&3) ^ ((r>>2)&3); source
// column pre-swizzled (global_load_lds dest stays lane-linear); reads conflict-
// free (verified round 3: SQ_LDS_BANK_CONFLICT = 0).
__global__ __launch_bounds__(512, 2) void gemm_i8(const int8_t* __restrict__ A,
                                                  const int8_t* __restrict__ B,
                                                  const float* __restrict__ rs,
                                                  const float* __restrict__ meanp,
                                                  float* __restrict__ out) {
    // T1: bijective XCD swizzle (512 wgs, 8 XCDs, 64 contiguous wgs per XCD)
    const int nwgx = N_OUT / 256;  // 16
    const int orig = blockIdx.y * nwgx + blockIdx.x;
    const int wg = (orig & 7) * 64 + (orig >> 3);
    const int bm = (wg / nwgx) * 256;
    const int bn = (wg % nwgx) * 256;

    __shared__ int8_t smem[4][2][16384];  // [slot][A,B][256 rows x 64 B]

    const int t0 = threadIdx.x;
    const int lane = t0 & 63;
    const int wave = t0 >> 6;
    const int wm = (wave >> 1) * 64;    // 0,64,128,192
    const int wn = (wave & 1) * 128;    // 0,128

    v16i accv[2][4] = {};

    // staging: thread t0 -> row R0 = t0>>2 (+128 for round 1), slot-chunk t0&3
    // holds source chunk (t0&3)^(R&3)^((R>>2)&3); row+128 leaves both terms
    // unchanged (128 == 0 mod 16).
    const int R0 = t0 >> 2;
    const int scol = (((t0 & 3) ^ (R0 & 3) ^ ((R0 >> 2) & 3)) << 4);
    const int8_t* Ag = A + (size_t)(bm + R0) * K_DIM + scol;
    const int8_t* Bg = B + (size_t)(bn + R0) * K_DIM + scol;
    int8_t* ldst = &smem[0][0][0] + (size_t)t0 * 16;

    // fragment read constants (A/B row = lane&31, 16B chunk = ks*2 + (lane>>5))
    const int l31 = lane & 31;
    const int lh = lane >> 5;
    const int sx = (l31 & 3) ^ ((l31 >> 2) & 3);
    const int co0 = ((lh ^ sx) << 4);        // ks=0 chunk byte offset
    const int co1 = (((2 + lh) ^ sx) << 4);  // ks=1 chunk byte offset
    const int offA0 = (wm + l31) * 64;
    const int offA1 = (wm + 32 + l31) * 64;
    const int offB0 = (wn + l31) * 64;
    const int offB1 = (wn + 32 + l31) * 64;
    const int offB2 = (wn + 64 + l31) * 64;
    const int offB3 = (wn + 96 + l31) * 64;

    // prologue: stage tiles 0..2 into slots 0..2
#pragma unroll
    for (int pt = 0; pt < 3; ++pt) {
        const int k0 = pt * 64;
        int8_t* sb = ldst + pt * 32768;
        gload_lds16(Ag + k0, sb);
        gload_lds16(Ag + k0 + (size_t)128 * K_DIM, sb + 8192);
        gload_lds16(Bg + k0, sb + 16384);
        gload_lds16(Bg + k0 + (size_t)128 * K_DIM, sb + 24576);
    }
    asm volatile("s_waitcnt vmcnt(8)" ::: "memory");  // tile 0 resident
    BAR();

    v4i ca0, ca1, cb0, cb1, cb2, cb3;  // ks0 frags (loaded one half-tile ahead)
    {
        const int8_t* aB = &smem[0][0][0];
        const int8_t* bB = &smem[0][1][0];
        ca0 = *(const v4i*)(aB + offA0 + co0);
        ca1 = *(const v4i*)(aB + offA1 + co0);
        cb0 = *(const v4i*)(bB + offB0 + co0);
        cb1 = *(const v4i*)(bB + offB1 + co0);
        cb2 = *(const v4i*)(bB + offB2 + co0);
        cb3 = *(const v4i*)(bB + offB3 + co0);
    }

#pragma unroll 1
    for (int t = 0; t < 64; ++t) {
        const int slot = t & 3;
        const int8_t* aB = &smem[slot][0][0];
        const int8_t* bB = &smem[slot][1][0];

        // stage tile t+3 into slot (t+3)&3 == (t-1)&3 (safe: last read pre-BAR t-1)
        if (t < 61) {
            const int ksg = (t + 3) * 64;
            int8_t* sb = ldst + ((t + 3) & 3) * 32768;
            gload_lds16(Ag + ksg, sb);
            gload_lds16(Ag + ksg + (size_t)128 * K_DIM, sb + 8192);
            gload_lds16(Bg + ksg, sb + 16384);
            gload_lds16(Bg + ksg + (size_t)128 * K_DIM, sb + 24576);
        }

        // ks1 frags of tile t (consumed after the barrier)
        v4i na0 = *(const v4i*)(aB + offA0 + co1);
        v4i na1 = *(const v4i*)(aB + offA1 + co1);
        v4i nb0 = *(const v4i*)(bB + offB0 + co1);
        v4i nb1 = *(const v4i*)(bB + offB1 + co1);
        v4i nb2 = *(const v4i*)(bB + offB2 + co1);
        v4i nb3 = *(const v4i*)(bB + offB3 + co1);

        __builtin_amdgcn_s_setprio(1);
        accv[0][0] = __builtin_amdgcn_mfma_i32_32x32x32_i8(ca0, cb0, accv[0][0], 0, 0, 0);
        accv[1][0] = __builtin_amdgcn_mfma_i32_32x32x32_i8(ca1, cb0, accv[1][0], 0, 0, 0);
        accv[0][1] = __builtin_amdgcn_mfma_i32_32x32x32_i8(ca0, cb1, accv[0][1], 0, 0, 0);
        accv[1][1] = __builtin_amdgcn_mfma_i32_32x32x32_i8(ca1, cb1, accv[1][1], 0, 0, 0);
        accv[0][2] = __builtin_amdgcn_mfma_i32_32x32x32_i8(ca0, cb2, accv[0][2], 0, 0, 0);
        accv[1][2] = __builtin_amdgcn_mfma_i32_32x32x32_i8(ca1, cb2, accv[1][2], 0, 0, 0);
        accv[0][3] = __builtin_amdgcn_mfma_i32_32x32x32_i8(ca0, cb3, accv[0][3], 0, 0, 0);
        accv[1][3] = __builtin_amdgcn_mfma_i32_32x32x32_i8(ca1, cb3, accv[1][3], 0, 0, 0);
        __builtin_amdgcn_s_setprio(0);

        // next tile resident; never vmcnt(0) in steady state
        if (t < 61) asm volatile("s_waitcnt vmcnt(8)" ::: "memory");
        else if (t == 61) asm volatile("s_waitcnt vmcnt(4)" ::: "memory");
        else if (t == 62) asm volatile("s_waitcnt vmcnt(0)" ::: "memory");
        if (t < 63) {
            BAR();
            // ks0 frags of tile t+1 (consumed next iteration)
            const int nslot = (t + 1) & 3;
            const int8_t* aN = &smem[nslot][0][0];
            const int8_t* bN = &smem[nslot][1][0];
            ca0 = *(const v4i*)(aN + offA0 + co0);
            ca1 = *(const v4i*)(aN + offA1 + co0);
            cb0 = *(const v4i*)(bN + offB0 + co0);
            cb1 = *(const v4i*)(bN + offB1 + co0);
            cb2 = *(const v4i*)(bN + offB2 + co0);
            cb3 = *(const v4i*)(bN + offB3 + co0);
        }

        __builtin_amdgcn_s_setprio(1);
        accv[0][0] = __builtin_amdgcn_mfma_i32_32x32x32_i8(na0, nb0, accv[0][0], 0, 0, 0);
        accv[1][0] = __builtin_amdgcn_mfma_i32_32x32x32_i8(na1, nb0, accv[1][0], 0, 0, 0);
        accv[0][1] = __builtin_amdgcn_mfma_i32_32x32x32_i8(na0, nb1, accv[0][1], 0, 0, 0);
        accv[1][1] = __builtin_amdgcn_mfma_i32_32x32x32_i8(na1, nb1, accv[1][1], 0, 0, 0);
        accv[0][2] = __builtin_amdgcn_mfma_i32_32x32x32_i8(na0, nb2, accv[0][2], 0, 0, 0);
        accv[1][2] = __builtin_amdgcn_mfma_i32_32x32x32_i8(na1, nb2, accv[1][2], 0, 0, 0);
        accv[0][3] = __builtin_amdgcn_mfma_i32_32x32x32_i8(na0, nb3, accv[0][3], 0, 0, 0);
        accv[1][3] = __builtin_amdgcn_mfma_i32_32x32x32_i8(na1, nb3, accv[1][3], 0, 0, 0);
        __builtin_amdgcn_s_setprio(0);
    }

    // epilogue: 32x32 C/D layout col=lane&31, row=(reg&3)+8*(reg>>2)+4*(lane>>5)
    const float wmean = *meanp;  // clamped mean|w| == 1/scale_w
#pragma unroll
    for (int m = 0; m < 2; ++m) {
#pragma unroll
        for (int r = 0; r < 16; ++r) {
            const int row = bm + wm + m * 32 + (r & 3) + 8 * (r >> 2) + 4 * lh;
            const float scale = rs[row] * wmean;
            float* orow = out + (size_t)row * N_OUT + bn + wn + l31;
#pragma unroll
            for (int n = 0; n < 4; ++n)
                orow[n * 32] = (float)accv[m][n][r] * scale;
        }
    }
}

extern "C" void kernel_launch(void* const* d_in, const int* in_sizes, int n_in,
                              void* d_out, int out_size, void* d_ws, size_t ws_size,
                              hipStream_t stream) {
    const float* x = (const float*)d_in[0];
    const float* w = (const float*)d_in[1];
    float* out = (float*)d_out;
    char* ws = (char*)d_ws;
    int8_t* q = (int8_t*)ws;
    int8_t* tw = (int8_t*)(ws + 33554432);
    float* rs = (float*)(ws + 50331648);
    double* partial = (double*)(ws + 50364416);
    float* meanp = (float*)(ws + 50372608);

    hipLaunchKernelGGL(quant_act, dim3(M_TOK), dim3(256), 0, stream, x, q, rs);
    hipLaunchKernelGGL(wabs_sum, dim3(1024), dim3(256), 0, stream, w, partial);
    hipLaunchKernelGGL(ternarize, dim3((N_OUT * (size_t)K_DIM / 16) / 256), dim3(256), 0, stream, w, tw, partial, meanp);
    hipLaunchKernelGGL(gemm_i8, dim3(N_OUT / 256, M_TOK / 256), dim3(512), 0, stream, q, tw, rs, meanp, out);
}